// Round 1
// baseline (1089.321 us; speedup 1.0000x reference)
//
#include <hip/hip_runtime.h>
#include <math.h>

#define NROWS 16384   // B*T
#define INCH  512
#define CH    2048
#define DD    256     // sum(Z_DIMS)
#define MM    1024    // codebook size
#define NHEAD 4
#define HD    64

// ---------------------------------------------------------------------------
// K1: H[N,CH] = X[N,INCH] @ W1[INCH,CH]   fp32, 128x128 tile, BK=8, 8x8/thread
// ---------------------------------------------------------------------------
__global__ __launch_bounds__(256) void k_gemm1(const float* __restrict__ X,
                                               const float* __restrict__ W1,
                                               float* __restrict__ H) {
  __shared__ float As[8][128];
  __shared__ float Bs[8][128];
  const int tid = threadIdx.x;
  const int tx = tid & 15, ty = tid >> 4;
  const int bm = blockIdx.y * 128, bn = blockIdx.x * 128;
  const int am = tid & 127;          // A row within tile
  const int ak = (tid >> 7) << 2;    // A k offset (0 or 4)
  const int bk = tid >> 5;           // B k row (0..7)
  const int bn4 = (tid & 31) << 2;   // B col (0..124)

  float acc[8][8];
#pragma unroll
  for (int i = 0; i < 8; ++i)
#pragma unroll
    for (int j = 0; j < 8; ++j) acc[i][j] = 0.f;

  const float* xg = &X[(size_t)(bm + am) * INCH + ak];
  const float* bg = &W1[(size_t)bk * CH + bn + bn4];

  for (int k0 = 0; k0 < INCH; k0 += 8) {
    float4 av = *(const float4*)(xg + k0);
    float4 bv = *(const float4*)(bg + (size_t)k0 * CH);
    __syncthreads();
    As[ak + 0][am] = av.x; As[ak + 1][am] = av.y;
    As[ak + 2][am] = av.z; As[ak + 3][am] = av.w;
    *(float4*)&Bs[bk][bn4] = bv;
    __syncthreads();
#pragma unroll
    for (int kk = 0; kk < 8; ++kk) {
      float a[8], b[8];
      *(float4*)&a[0] = *(const float4*)&As[kk][ty * 4];
      *(float4*)&a[4] = *(const float4*)&As[kk][64 + ty * 4];
      *(float4*)&b[0] = *(const float4*)&Bs[kk][tx * 4];
      *(float4*)&b[4] = *(const float4*)&Bs[kk][64 + tx * 4];
#pragma unroll
      for (int i = 0; i < 8; ++i)
#pragma unroll
        for (int j = 0; j < 8; ++j) acc[i][j] = fmaf(a[i], b[j], acc[i][j]);
    }
  }
#pragma unroll
  for (int qi = 0; qi < 2; ++qi)
#pragma unroll
    for (int i = 0; i < 4; ++i) {
      const int r = bm + qi * 64 + ty * 4 + i;
#pragma unroll
      for (int qj = 0; qj < 2; ++qj) {
        float4 v = make_float4(acc[qi * 4 + i][qj * 4 + 0], acc[qi * 4 + i][qj * 4 + 1],
                               acc[qi * 4 + i][qj * 4 + 2], acc[qi * 4 + i][qj * 4 + 3]);
        *(float4*)&H[(size_t)r * CH + bn + qj * 64 + tx * 4] = v;
      }
    }
}

// ---------------------------------------------------------------------------
// K2: in-place LayerNorm (biased var) + ReLU over rows of H. One block per row.
// ---------------------------------------------------------------------------
__global__ __launch_bounds__(256) void k_ln_relu(float* __restrict__ H,
                                                 const float* __restrict__ g,
                                                 const float* __restrict__ b) {
  __shared__ float red[8];
  const int row = blockIdx.x;
  const int tid = threadIdx.x;
  float4* hp = (float4*)&H[(size_t)row * CH];
  float4 v0 = hp[tid];
  float4 v1 = hp[tid + 256];
  float s  = v0.x + v0.y + v0.z + v0.w + v1.x + v1.y + v1.z + v1.w;
  float ss = v0.x * v0.x + v0.y * v0.y + v0.z * v0.z + v0.w * v0.w +
             v1.x * v1.x + v1.y * v1.y + v1.z * v1.z + v1.w * v1.w;
#pragma unroll
  for (int m = 32; m; m >>= 1) { s += __shfl_xor(s, m); ss += __shfl_xor(ss, m); }
  if ((tid & 63) == 0) { red[(tid >> 6) * 2] = s; red[(tid >> 6) * 2 + 1] = ss; }
  __syncthreads();
  s  = red[0] + red[2] + red[4] + red[6];
  ss = red[1] + red[3] + red[5] + red[7];
  const float mu  = s * (1.f / CH);
  const float var = ss * (1.f / CH) - mu * mu;
  const float rinv = 1.f / sqrtf(var + 1e-5f);
  float4 g0 = ((const float4*)g)[tid], g1 = ((const float4*)g)[tid + 256];
  float4 b0 = ((const float4*)b)[tid], b1 = ((const float4*)b)[tid + 256];
  v0.x = fmaxf((v0.x - mu) * rinv * g0.x + b0.x, 0.f);
  v0.y = fmaxf((v0.y - mu) * rinv * g0.y + b0.y, 0.f);
  v0.z = fmaxf((v0.z - mu) * rinv * g0.z + b0.z, 0.f);
  v0.w = fmaxf((v0.w - mu) * rinv * g0.w + b0.w, 0.f);
  v1.x = fmaxf((v1.x - mu) * rinv * g1.x + b1.x, 0.f);
  v1.y = fmaxf((v1.y - mu) * rinv * g1.y + b1.y, 0.f);
  v1.z = fmaxf((v1.z - mu) * rinv * g1.z + b1.z, 0.f);
  v1.w = fmaxf((v1.w - mu) * rinv * g1.w + b1.w, 0.f);
  hp[tid] = v0;
  hp[tid + 256] = v1;
}

// ---------------------------------------------------------------------------
// K3: Z[N,256] = H[N,2048] @ W2 + b2, fused per-head (64-wide) log_softmax -> P
// BM=64, BN=256 (all heads in-block so full rows are available for LSE)
// thread: tx=cols (4 per head quadrant), ty=rows (4)
// ---------------------------------------------------------------------------
__global__ __launch_bounds__(256) void k_gemm2_lse(const float* __restrict__ H,
                                                   const float* __restrict__ W2,
                                                   const float* __restrict__ b2,
                                                   float* __restrict__ Z,
                                                   float* __restrict__ P) {
  __shared__ float As[8][64];
  __shared__ float Bs[8][256];
  const int tid = threadIdx.x;
  const int tx = tid & 15, ty = tid >> 4;
  const int bm = blockIdx.x * 64;

  float acc[4][16];
#pragma unroll
  for (int i = 0; i < 4; ++i)
#pragma unroll
    for (int j = 0; j < 16; ++j) acc[i][j] = 0.f;

  for (int k0 = 0; k0 < CH; k0 += 8) {
    float4 av;
    if (tid < 128)
      av = *(const float4*)&H[(size_t)(bm + (tid & 63)) * CH + k0 + ((tid >> 6) << 2)];
    float4 bv0 = *(const float4*)&W2[(size_t)(k0 + (tid >> 6)) * DD + (tid & 63) * 4];
    float4 bv1 = *(const float4*)&W2[(size_t)(k0 + 4 + (tid >> 6)) * DD + (tid & 63) * 4];
    __syncthreads();
    if (tid < 128) {
      const int ak = (tid >> 6) << 2, am = tid & 63;
      As[ak + 0][am] = av.x; As[ak + 1][am] = av.y;
      As[ak + 2][am] = av.z; As[ak + 3][am] = av.w;
    }
    *(float4*)&Bs[tid >> 6][(tid & 63) * 4] = bv0;
    *(float4*)&Bs[4 + (tid >> 6)][(tid & 63) * 4] = bv1;
    __syncthreads();
#pragma unroll
    for (int kk = 0; kk < 8; ++kk) {
      float a[4], b[16];
      *(float4*)&a[0] = *(const float4*)&As[kk][ty * 4];
#pragma unroll
      for (int q = 0; q < 4; ++q)
        *(float4*)&b[q * 4] = *(const float4*)&Bs[kk][q * 64 + tx * 4];
#pragma unroll
      for (int i = 0; i < 4; ++i)
#pragma unroll
        for (int j = 0; j < 16; ++j) acc[i][j] = fmaf(a[i], b[j], acc[i][j]);
    }
  }

  // epilogue: bias + per-head log_softmax (16 tx lanes hold one head's 64 cols)
#pragma unroll
  for (int q = 0; q < 4; ++q) {
    const float4 bias = *(const float4*)&b2[q * 64 + tx * 4];
#pragma unroll
    for (int i = 0; i < 4; ++i) {
      float z0 = acc[i][q * 4 + 0] + bias.x;
      float z1 = acc[i][q * 4 + 1] + bias.y;
      float z2 = acc[i][q * 4 + 2] + bias.z;
      float z3 = acc[i][q * 4 + 3] + bias.w;
      float mx = fmaxf(fmaxf(z0, z1), fmaxf(z2, z3));
#pragma unroll
      for (int m = 1; m <= 8; m <<= 1) mx = fmaxf(mx, __shfl_xor(mx, m));
      float se = expf(z0 - mx) + expf(z1 - mx) + expf(z2 - mx) + expf(z3 - mx);
#pragma unroll
      for (int m = 1; m <= 8; m <<= 1) se += __shfl_xor(se, m);
      const float lse = mx + logf(se);
      const int r = bm + ty * 4 + i;
      *(float4*)&Z[(size_t)r * DD + q * 64 + tx * 4] = make_float4(z0, z1, z2, z3);
      *(float4*)&P[(size_t)r * DD + q * 64 + tx * 4] =
          make_float4(z0 - lse, z1 - lse, z2 - lse, z3 - lse);
    }
  }
}

// ---------------------------------------------------------------------------
// K4: logE = log(embedding)
// ---------------------------------------------------------------------------
__global__ __launch_bounds__(256) void k_logemb(const float* __restrict__ E,
                                                float* __restrict__ LE, int n) {
  const int i = blockIdx.x * 256 + threadIdx.x;
  if (i < n) LE[i] = logf(E[i]);
}

// ---------------------------------------------------------------------------
// K5: codebook search. Per block: 64 rows. ex = exp(p) in LDS, self = <ex,p>.
// kl_n = min_m (self - <ex, logE_m>) = self - max_m dot. Fused gather of Q.
// threads: tx (16, m-dir x4) * ty (16, rows x4: ty, ty+16, ty+32, ty+48)
// ---------------------------------------------------------------------------
__global__ __launch_bounds__(256) void k_codebook(const float* __restrict__ P,
                                                  const float* __restrict__ LE,
                                                  const float* __restrict__ E,
                                                  float* __restrict__ Q,
                                                  float* __restrict__ KL) {
  __shared__ float exs[64][260];   // 256 + pad(4) -> f4-aligned, conflict-free reads
  __shared__ float Bs[64][64];     // logE tile, xor-swizzled columns
  __shared__ int   sidx[64];
  const int tid = threadIdx.x;
  const int tx = tid & 15, ty = tid >> 4;
  const int row0 = blockIdx.x * 64;

  float self_[4];
#pragma unroll
  for (int rr = 0; rr < 4; ++rr) {
    const int r = ty + rr * 16;
    float s = 0.f;
    const float4* pp = (const float4*)&P[(size_t)(row0 + r) * DD + tx * 16];
#pragma unroll
    for (int q = 0; q < 4; ++q) {
      float4 v = pp[q];
      float e0 = expf(v.x), e1 = expf(v.y), e2 = expf(v.z), e3 = expf(v.w);
      s += e0 * v.x + e1 * v.y + e2 * v.z + e3 * v.w;
      *(float4*)&exs[r][tx * 16 + q * 4] = make_float4(e0, e1, e2, e3);
    }
#pragma unroll
    for (int m = 8; m; m >>= 1) s += __shfl_xor(s, m);
    self_[rr] = s;
  }
  __syncthreads();

  float best[4] = {-1e30f, -1e30f, -1e30f, -1e30f};
  int bidx[4] = {0, 0, 0, 0};

  for (int mt = 0; mt < MM; mt += 64) {
    float acc[4][4];
#pragma unroll
    for (int rr = 0; rr < 4; ++rr)
#pragma unroll
      for (int j = 0; j < 4; ++j) acc[rr][j] = 0.f;

    for (int kt = 0; kt < DD; kt += 64) {
      __syncthreads();
#pragma unroll
      for (int q = 0; q < 4; ++q) {
        const int f = tid + 256 * q;          // 0..1023
        const int m = f >> 4, c4 = f & 15;
        float4 v = *(const float4*)&LE[(size_t)(mt + m) * DD + kt + c4 * 4];
        const int cs = c4 ^ ((m >> 2) & 7);   // bank swizzle
        *(float4*)&Bs[m][cs * 4] = v;
      }
      __syncthreads();
#pragma unroll
      for (int k4 = 0; k4 < 16; ++k4) {
        float4 bvec[4];
#pragma unroll
        for (int j = 0; j < 4; ++j)
          bvec[j] = *(const float4*)&Bs[tx * 4 + j][(k4 ^ (tx & 7)) * 4];
#pragma unroll
        for (int rr = 0; rr < 4; ++rr) {
          // NOTE: exs column for swizzled read k4^(tx&7) must match B's k -> use same k!
          float4 av = *(const float4*)&exs[ty + rr * 16][kt + (k4 ^ (tx & 7)) * 4];
#pragma unroll
          for (int j = 0; j < 4; ++j)
            acc[rr][j] = fmaf(av.x, bvec[j].x,
                        fmaf(av.y, bvec[j].y,
                        fmaf(av.z, bvec[j].z,
                        fmaf(av.w, bvec[j].w, acc[rr][j]))));
        }
      }
    }
    // argmax(dot) with first-index tie-break == argmin(div)
#pragma unroll
    for (int rr = 0; rr < 4; ++rr) {
      float bv = acc[rr][0];
      int bi = mt + tx * 4;
#pragma unroll
      for (int j = 1; j < 4; ++j)
        if (acc[rr][j] > bv) { bv = acc[rr][j]; bi = mt + tx * 4 + j; }
#pragma unroll
      for (int msk = 8; msk; msk >>= 1) {
        float ov = __shfl_xor(bv, msk);
        int   oi = __shfl_xor(bi, msk);
        if (ov > bv || (ov == bv && oi < bi)) { bv = ov; bi = oi; }
      }
      if (bv > best[rr]) { best[rr] = bv; bidx[rr] = bi; }
    }
  }

  if (tx == 0) {
#pragma unroll
    for (int rr = 0; rr < 4; ++rr) {
      const int r = ty + rr * 16;
      sidx[r] = bidx[rr];
      KL[row0 + r] = self_[rr] - best[rr];
    }
  }
  __syncthreads();
  // gather quantized rows: 64 rows x 64 float4
#pragma unroll
  for (int q = 0; q < 16; ++q) {
    const int f = tid + 256 * q;
    const int r = f >> 6, c4 = f & 63;
    float4 v = *(const float4*)&E[(size_t)sidx[r] * DD + c4 * 4];
    *(float4*)&Q[(size_t)(row0 + r) * DD + c4 * 4] = v;
  }
}

// ---------------------------------------------------------------------------
// K6: deterministic loss reduction: loss = 0.25/B * sum_n kl[n]*mask[n]
// ---------------------------------------------------------------------------
__global__ __launch_bounds__(256) void k_loss(const float* __restrict__ KL,
                                              const float* __restrict__ MASK,
                                              float* __restrict__ out) {
  __shared__ float red[4];
  const int tid = threadIdx.x;
  float s = 0.f;
  for (int i = tid; i < NROWS; i += 256) s += KL[i] * MASK[i];
#pragma unroll
  for (int m = 32; m; m >>= 1) s += __shfl_xor(s, m);
  if ((tid & 63) == 0) red[tid >> 6] = s;
  __syncthreads();
  if (tid == 0) out[0] = (red[0] + red[1] + red[2] + red[3]) * (0.25f / 16.f);
}

// ---------------------------------------------------------------------------
extern "C" void kernel_launch(void* const* d_in, const int* in_sizes, int n_in,
                              void* d_out, int out_size, void* d_ws, size_t ws_size,
                              hipStream_t stream) {
  const float* x     = (const float*)d_in[0];
  const float* masks = (const float*)d_in[1];
  const float* W1    = (const float*)d_in[2];
  const float* ln_g  = (const float*)d_in[3];
  const float* ln_b  = (const float*)d_in[4];
  const float* W2    = (const float*)d_in[5];
  const float* b2    = (const float*)d_in[6];
  const float* emb   = (const float*)d_in[7];

  float* z_out = (float*)d_out;
  float* q_out = z_out + (size_t)NROWS * DD;
  float* loss_out = z_out + 2 * (size_t)NROWS * DD;

  char* ws = (char*)d_ws;
  float* H   = (float*)ws;                        // 16384*2048*4 = 134217728 B
  float* P   = (float*)(ws + 134217728);          // 16384*256*4  =  16777216 B
  float* LE  = (float*)(ws + 150994944);          // 1024*256*4   =   1048576 B
  float* KL  = (float*)(ws + 152043520);          // 16384*4      =     65536 B

  k_gemm1<<<dim3(16, 128), 256, 0, stream>>>(x, W1, H);
  k_ln_relu<<<NROWS, 256, 0, stream>>>(H, ln_g, ln_b);
  k_gemm2_lse<<<dim3(NROWS / 64), 256, 0, stream>>>(H, W2, b2, z_out, P);
  k_logemb<<<dim3((MM * DD) / 256), 256, 0, stream>>>(emb, LE, MM * DD);
  k_codebook<<<dim3(NROWS / 64), 256, 0, stream>>>(P, LE, emb, q_out, KL);
  k_loss<<<1, 256, 0, stream>>>(KL, masks, loss_out);
}

// Round 2
// 1022.342 us; speedup vs baseline: 1.0655x; 1.0655x over previous
//
#include <hip/hip_runtime.h>
#include <math.h>

#define NROWS 16384   // B*T
#define HALF_ROWS 8192
#define INCH  512
#define CH    2048
#define DD    256
#define MM    1024

typedef unsigned short u16;
typedef short short8 __attribute__((ext_vector_type(8)));
typedef float f32x4 __attribute__((ext_vector_type(4)));

__device__ __forceinline__ u16 f2bf(float f) {
  unsigned u = __float_as_uint(f);
  return (u16)((u + 0x7fffu + ((u >> 16) & 1u)) >> 16);
}
__device__ __forceinline__ float bf2f(u16 h) {
  return __uint_as_float(((unsigned)h) << 16);
}
__device__ __forceinline__ void gload16(const u16* g, u16* lds) {
  __builtin_amdgcn_global_load_lds((const __attribute__((address_space(1))) void*)g,
                                   (__attribute__((address_space(3))) void*)lds, 16, 0, 0);
}

// ---------------------------------------------------------------------------
// split kernels: fp32 -> bf16 hi/lo pair
// ---------------------------------------------------------------------------
__global__ __launch_bounds__(256) void k_split_x(const float* __restrict__ x,
                                                 u16* __restrict__ xh, u16* __restrict__ xl) {
  const size_t i = ((size_t)blockIdx.x * 256 + threadIdx.x) * 8;
  float4 a = *(const float4*)(x + i);
  float4 b = *(const float4*)(x + i + 4);
  float v[8] = {a.x, a.y, a.z, a.w, b.x, b.y, b.z, b.w};
  unsigned hw[4], lw[4];
#pragma unroll
  for (int p = 0; p < 4; ++p) {
    u16 h0 = f2bf(v[2*p]), h1 = f2bf(v[2*p+1]);
    u16 l0 = f2bf(v[2*p] - bf2f(h0)), l1 = f2bf(v[2*p+1] - bf2f(h1));
    hw[p] = (unsigned)h0 | ((unsigned)h1 << 16);
    lw[p] = (unsigned)l0 | ((unsigned)l1 << 16);
  }
  *(uint4*)(xh + i) = make_uint4(hw[0], hw[1], hw[2], hw[3]);
  *(uint4*)(xl + i) = make_uint4(lw[0], lw[1], lw[2], lw[3]);
}

// src [R][C] fp32  ->  dh/dl [C][R] bf16 hi/lo   (transpose + split)
__global__ __launch_bounds__(256) void k_split_wT(const float* __restrict__ src,
                                                  u16* __restrict__ dh, u16* __restrict__ dl,
                                                  int R, int C) {
  __shared__ float t[32][33];
  const int tx = threadIdx.x & 31, ty = threadIdx.x >> 5;
  const int c0 = blockIdx.x * 32, r0 = blockIdx.y * 32;
#pragma unroll
  for (int i = 0; i < 4; ++i)
    t[ty + i * 8][tx] = src[(size_t)(r0 + ty + i * 8) * C + c0 + tx];
  __syncthreads();
#pragma unroll
  for (int i = 0; i < 4; ++i) {
    float v = t[tx][ty + i * 8];
    size_t o = (size_t)(c0 + ty + i * 8) * R + r0 + tx;
    u16 h = f2bf(v);
    dh[o] = h;
    dl[o] = f2bf(v - bf2f(h));
  }
}

// ---------------------------------------------------------------------------
// K1: H(split) = X @ W1 via split-bf16 MFMA. 128x128 tile, BK=32, 4 waves.
// LDS chunk layout per matrix: chunk = kc*128 + row (16B chunks, frag-major)
// regions (chunk units): Ah 0, Al 512, Bh 1024, Bl 1536
// ---------------------------------------------------------------------------
__global__ __launch_bounds__(256) void k_gemm1(const u16* __restrict__ Xh, const u16* __restrict__ Xl,
                                               const u16* __restrict__ W1ht, const u16* __restrict__ W1lt,
                                               u16* __restrict__ Hh, u16* __restrict__ Hl) {
  __shared__ u16 sm[2][2048 * 8];
  const int tid = threadIdx.x;
  const int lane = tid & 63, w = tid >> 6;
  const int wr = w >> 1, wc = w & 1;
  const int gm = blockIdx.y * 128, n0 = blockIdx.x * 128;

  const u16* srcbase = (w == 0) ? Xh : (w == 1) ? Xl : (w == 2) ? W1ht : W1lt;
  const int rowbase = (w < 2) ? gm : n0;

  f32x4 acc[4][4];
#pragma unroll
  for (int i = 0; i < 4; ++i)
#pragma unroll
    for (int j = 0; j < 4; ++j) acc[i][j] = (f32x4){0.f, 0.f, 0.f, 0.f};

  auto STAGE = [&](int buf, int kt) {
#pragma unroll
    for (int t = 0; t < 8; ++t) {
      int c = t * 64 + lane;
      int kc = c >> 7, r = c & 127;
      const u16* g = srcbase + ((size_t)(rowbase + r) << 9) + (kt << 5) + (kc << 3);
      gload16(g, &sm[buf][(w * 512 + t * 64) * 8]);
    }
  };

  STAGE(0, 0);
  for (int kt = 0; kt < 16; ++kt) {
    __syncthreads();                       // vmcnt(0) drain -> buf[kt&1] ready
    if (kt + 1 < 16) STAGE((kt + 1) & 1, kt + 1);
    const u16* base = sm[kt & 1];
    const int lr = lane & 15, kc = lane >> 4;
    short8 ah[4], al[4], bh[4], bl[4];
#pragma unroll
    for (int i = 0; i < 4; ++i) {
      ah[i] = *(const short8*)(base + (kc * 128 + wr * 64 + i * 16 + lr) * 8);
      al[i] = *(const short8*)(base + (512 + kc * 128 + wr * 64 + i * 16 + lr) * 8);
      bh[i] = *(const short8*)(base + (1024 + kc * 128 + wc * 64 + i * 16 + lr) * 8);
      bl[i] = *(const short8*)(base + (1536 + kc * 128 + wc * 64 + i * 16 + lr) * 8);
    }
#pragma unroll
    for (int i = 0; i < 4; ++i)
#pragma unroll
      for (int j = 0; j < 4; ++j) {
        acc[i][j] = __builtin_amdgcn_mfma_f32_16x16x32_bf16(ah[i], bh[j], acc[i][j], 0, 0, 0);
        acc[i][j] = __builtin_amdgcn_mfma_f32_16x16x32_bf16(ah[i], bl[j], acc[i][j], 0, 0, 0);
        acc[i][j] = __builtin_amdgcn_mfma_f32_16x16x32_bf16(al[i], bh[j], acc[i][j], 0, 0, 0);
      }
  }

  const int rr = (lane >> 4) << 2, cc = lane & 15;
#pragma unroll
  for (int i = 0; i < 4; ++i)
#pragma unroll
    for (int j = 0; j < 4; ++j) {
#pragma unroll
      for (int reg = 0; reg < 4; ++reg) {
        size_t o = (size_t)(gm + wr * 64 + i * 16 + rr + reg) * CH + (n0 + wc * 64 + j * 16 + cc);
        float v = acc[i][j][reg];
        u16 h = f2bf(v);
        Hh[o] = h;
        Hl[o] = f2bf(v - bf2f(h));
      }
    }
}

// ---------------------------------------------------------------------------
// K2: in-place LayerNorm + ReLU on split H. One block per row.
// ---------------------------------------------------------------------------
__global__ __launch_bounds__(256) void k_ln(u16* __restrict__ Hh, u16* __restrict__ Hl,
                                            const float* __restrict__ g, const float* __restrict__ b) {
  __shared__ float red[8];
  const int row = blockIdx.x;
  const int tid = threadIdx.x;
  uint4* hp = (uint4*)(Hh + (size_t)row * CH);
  uint4* lp = (uint4*)(Hl + (size_t)row * CH);
  uint4 hh = hp[tid], ll = lp[tid];
  float f[8];
  {
    unsigned hw[4] = {hh.x, hh.y, hh.z, hh.w};
    unsigned lw[4] = {ll.x, ll.y, ll.z, ll.w};
#pragma unroll
    for (int p = 0; p < 4; ++p) {
      f[2*p]   = bf2f((u16)(hw[p] & 0xffffu)) + bf2f((u16)(lw[p] & 0xffffu));
      f[2*p+1] = bf2f((u16)(hw[p] >> 16))     + bf2f((u16)(lw[p] >> 16));
    }
  }
  float s = 0.f, ss = 0.f;
#pragma unroll
  for (int j = 0; j < 8; ++j) { s += f[j]; ss += f[j] * f[j]; }
#pragma unroll
  for (int m = 32; m; m >>= 1) { s += __shfl_xor(s, m); ss += __shfl_xor(ss, m); }
  if ((tid & 63) == 0) { red[(tid >> 6) * 2] = s; red[(tid >> 6) * 2 + 1] = ss; }
  __syncthreads();
  s  = red[0] + red[2] + red[4] + red[6];
  ss = red[1] + red[3] + red[5] + red[7];
  const float mu  = s * (1.f / CH);
  const float var = ss * (1.f / CH) - mu * mu;
  const float rinv = 1.f / sqrtf(var + 1e-5f);
  float4 g0 = ((const float4*)g)[tid * 2], g1 = ((const float4*)g)[tid * 2 + 1];
  float4 b0 = ((const float4*)b)[tid * 2], b1 = ((const float4*)b)[tid * 2 + 1];
  float gg[8] = {g0.x, g0.y, g0.z, g0.w, g1.x, g1.y, g1.z, g1.w};
  float bb[8] = {b0.x, b0.y, b0.z, b0.w, b1.x, b1.y, b1.z, b1.w};
  unsigned hw[4], lw[4];
#pragma unroll
  for (int p = 0; p < 4; ++p) {
    float y0 = fmaxf((f[2*p]   - mu) * rinv * gg[2*p]   + bb[2*p],   0.f);
    float y1 = fmaxf((f[2*p+1] - mu) * rinv * gg[2*p+1] + bb[2*p+1], 0.f);
    u16 h0 = f2bf(y0), h1 = f2bf(y1);
    u16 l0 = f2bf(y0 - bf2f(h0)), l1 = f2bf(y1 - bf2f(h1));
    hw[p] = (unsigned)h0 | ((unsigned)h1 << 16);
    lw[p] = (unsigned)l0 | ((unsigned)l1 << 16);
  }
  hp[tid] = make_uint4(hw[0], hw[1], hw[2], hw[3]);
  lp[tid] = make_uint4(lw[0], lw[1], lw[2], lw[3]);
}

// ---------------------------------------------------------------------------
// K3: Z = H @ W2 + b2, fused per-head log_softmax -> P. Split-bf16 MFMA.
// BM=64, BN=128, BK=32, 4 waves; wave w owns rows w*16..w*16+15, all 128 cols.
// LDS regions (chunk units): Ah 0(256), Al 256, Bh 512(512), Bl 1024
// ---------------------------------------------------------------------------
__global__ __launch_bounds__(256) void k_gemm2(const u16* __restrict__ Hh, const u16* __restrict__ Hl,
                                               const u16* __restrict__ W2ht, const u16* __restrict__ W2lt,
                                               const float* __restrict__ b2,
                                               float* __restrict__ Z, float* __restrict__ P) {
  __shared__ u16 sm[2][1536 * 8];
  const int tid = threadIdx.x;
  const int lane = tid & 63, w = tid >> 6;
  const int gm = blockIdx.y * 64, n0 = blockIdx.x * 128;

  f32x4 acc[8];
#pragma unroll
  for (int j = 0; j < 8; ++j) acc[j] = (f32x4){0.f, 0.f, 0.f, 0.f};

  auto STAGE = [&](int buf, int kt) {
#pragma unroll
    for (int t = 0; t < 6; ++t) {
      int v = w * 384 + t * 64 + lane;
      bool isA = v < 512;
      int ca = v & 255, cb = v & 511;
      int kc = isA ? (ca >> 6) : (cb >> 7);
      int row = isA ? (gm + (ca & 63)) : (n0 + (cb & 127));
      const u16* sb = (v < 256) ? Hh : (v < 512) ? Hl : (v < 1024) ? W2ht : W2lt;
      const u16* g = sb + ((size_t)row << 11) + (kt << 5) + (kc << 3);
      gload16(g, &sm[buf][(w * 384 + t * 64) * 8]);
    }
  };

  STAGE(0, 0);
  for (int kt = 0; kt < 64; ++kt) {
    __syncthreads();
    if (kt + 1 < 64) STAGE((kt + 1) & 1, kt + 1);
    const u16* base = sm[kt & 1];
    const int lr = lane & 15, kc = lane >> 4;
    short8 ah = *(const short8*)(base + (kc * 64 + w * 16 + lr) * 8);
    short8 al = *(const short8*)(base + (256 + kc * 64 + w * 16 + lr) * 8);
    short8 bh[8], bl[8];
#pragma unroll
    for (int j = 0; j < 8; ++j) {
      bh[j] = *(const short8*)(base + (512 + kc * 128 + j * 16 + lr) * 8);
      bl[j] = *(const short8*)(base + (1024 + kc * 128 + j * 16 + lr) * 8);
    }
#pragma unroll
    for (int j = 0; j < 8; ++j) {
      acc[j] = __builtin_amdgcn_mfma_f32_16x16x32_bf16(ah, bh[j], acc[j], 0, 0, 0);
      acc[j] = __builtin_amdgcn_mfma_f32_16x16x32_bf16(ah, bl[j], acc[j], 0, 0, 0);
      acc[j] = __builtin_amdgcn_mfma_f32_16x16x32_bf16(al, bh[j], acc[j], 0, 0, 0);
    }
  }

  // epilogue: bias + per-head LSE (head = 64 cols = 4 col-subtiles, intra-wave)
  const int cc = lane & 15;
  float bias[8];
#pragma unroll
  for (int j = 0; j < 8; ++j) bias[j] = b2[n0 + j * 16 + cc];
#pragma unroll
  for (int j = 0; j < 8; ++j)
#pragma unroll
    for (int reg = 0; reg < 4; ++reg) acc[j][reg] += bias[j];

  const int rr = (lane >> 4) << 2;
#pragma unroll
  for (int reg = 0; reg < 4; ++reg) {
    const int row = gm + w * 16 + rr + reg;
#pragma unroll
    for (int hd = 0; hd < 2; ++hd) {
      float mx = fmaxf(fmaxf(acc[hd*4+0][reg], acc[hd*4+1][reg]),
                       fmaxf(acc[hd*4+2][reg], acc[hd*4+3][reg]));
#pragma unroll
      for (int m = 1; m <= 8; m <<= 1) mx = fmaxf(mx, __shfl_xor(mx, m));
      float se = expf(acc[hd*4+0][reg] - mx) + expf(acc[hd*4+1][reg] - mx) +
                 expf(acc[hd*4+2][reg] - mx) + expf(acc[hd*4+3][reg] - mx);
#pragma unroll
      for (int m = 1; m <= 8; m <<= 1) se += __shfl_xor(se, m);
      const float lse = mx + logf(se);
#pragma unroll
      for (int j4 = 0; j4 < 4; ++j4) {
        const int col = n0 + (hd * 4 + j4) * 16 + cc;
        const size_t o = (size_t)row * DD + col;
        const float zv = acc[hd*4+j4][reg];
        Z[o] = zv;
        P[o] = zv - lse;
      }
    }
  }
}

// ---------------------------------------------------------------------------
// K4: logE = log(embedding)
// ---------------------------------------------------------------------------
__global__ __launch_bounds__(256) void k_logemb(const float* __restrict__ E,
                                                float* __restrict__ LE, int n) {
  const int i = blockIdx.x * 256 + threadIdx.x;
  if (i < n) LE[i] = logf(E[i]);
}

// ---------------------------------------------------------------------------
// K5: codebook search (fp32, unchanged from R0)
// ---------------------------------------------------------------------------
__global__ __launch_bounds__(256) void k_codebook(const float* __restrict__ P,
                                                  const float* __restrict__ LE,
                                                  const float* __restrict__ E,
                                                  float* __restrict__ Q,
                                                  float* __restrict__ KL) {
  __shared__ float exs[64][260];
  __shared__ float Bs[64][64];
  __shared__ int   sidx[64];
  const int tid = threadIdx.x;
  const int tx = tid & 15, ty = tid >> 4;
  const int row0 = blockIdx.x * 64;

  float self_[4];
#pragma unroll
  for (int rr = 0; rr < 4; ++rr) {
    const int r = ty + rr * 16;
    float s = 0.f;
    const float4* pp = (const float4*)&P[(size_t)(row0 + r) * DD + tx * 16];
#pragma unroll
    for (int q = 0; q < 4; ++q) {
      float4 v = pp[q];
      float e0 = expf(v.x), e1 = expf(v.y), e2 = expf(v.z), e3 = expf(v.w);
      s += e0 * v.x + e1 * v.y + e2 * v.z + e3 * v.w;
      *(float4*)&exs[r][tx * 16 + q * 4] = make_float4(e0, e1, e2, e3);
    }
#pragma unroll
    for (int m = 8; m; m >>= 1) s += __shfl_xor(s, m);
    self_[rr] = s;
  }
  __syncthreads();

  float best[4] = {-1e30f, -1e30f, -1e30f, -1e30f};
  int bidx[4] = {0, 0, 0, 0};

  for (int mt = 0; mt < MM; mt += 64) {
    float acc[4][4];
#pragma unroll
    for (int rr = 0; rr < 4; ++rr)
#pragma unroll
      for (int j = 0; j < 4; ++j) acc[rr][j] = 0.f;

    for (int kt = 0; kt < DD; kt += 64) {
      __syncthreads();
#pragma unroll
      for (int q = 0; q < 4; ++q) {
        const int f = tid + 256 * q;
        const int m = f >> 4, c4 = f & 15;
        float4 v = *(const float4*)&LE[(size_t)(mt + m) * DD + kt + c4 * 4];
        const int cs = c4 ^ ((m >> 2) & 7);
        *(float4*)&Bs[m][cs * 4] = v;
      }
      __syncthreads();
#pragma unroll
      for (int k4 = 0; k4 < 16; ++k4) {
        float4 bvec[4];
#pragma unroll
        for (int j = 0; j < 4; ++j)
          bvec[j] = *(const float4*)&Bs[tx * 4 + j][(k4 ^ (tx & 7)) * 4];
#pragma unroll
        for (int rr = 0; rr < 4; ++rr) {
          float4 av = *(const float4*)&exs[ty + rr * 16][kt + (k4 ^ (tx & 7)) * 4];
#pragma unroll
          for (int j = 0; j < 4; ++j)
            acc[rr][j] = fmaf(av.x, bvec[j].x,
                        fmaf(av.y, bvec[j].y,
                        fmaf(av.z, bvec[j].z,
                        fmaf(av.w, bvec[j].w, acc[rr][j]))));
        }
      }
    }
#pragma unroll
    for (int rr = 0; rr < 4; ++rr) {
      float bv = acc[rr][0];
      int bi = mt + tx * 4;
#pragma unroll
      for (int j = 1; j < 4; ++j)
        if (acc[rr][j] > bv) { bv = acc[rr][j]; bi = mt + tx * 4 + j; }
#pragma unroll
      for (int msk = 8; msk; msk >>= 1) {
        float ov = __shfl_xor(bv, msk);
        int   oi = __shfl_xor(bi, msk);
        if (ov > bv || (ov == bv && oi < bi)) { bv = ov; bi = oi; }
      }
      if (bv > best[rr]) { best[rr] = bv; bidx[rr] = bi; }
    }
  }

  if (tx == 0) {
#pragma unroll
    for (int rr = 0; rr < 4; ++rr) {
      const int r = ty + rr * 16;
      sidx[r] = bidx[rr];
      KL[row0 + r] = self_[rr] - best[rr];
    }
  }
  __syncthreads();
#pragma unroll
  for (int q = 0; q < 16; ++q) {
    const int f = tid + 256 * q;
    const int r = f >> 6, c4 = f & 63;
    float4 v = *(const float4*)&E[(size_t)sidx[r] * DD + c4 * 4];
    *(float4*)&Q[(size_t)(row0 + r) * DD + c4 * 4] = v;
  }
}

// ---------------------------------------------------------------------------
// K6: loss = 0.25/B * sum_n kl[n]*mask[n]
// ---------------------------------------------------------------------------
__global__ __launch_bounds__(256) void k_loss(const float* __restrict__ KL,
                                              const float* __restrict__ MASK,
                                              float* __restrict__ out) {
  __shared__ float red[4];
  const int tid = threadIdx.x;
  float s = 0.f;
  for (int i = tid; i < NROWS; i += 256) s += KL[i] * MASK[i];
#pragma unroll
  for (int m = 32; m; m >>= 1) s += __shfl_xor(s, m);
  if ((tid & 63) == 0) red[tid >> 6] = s;
  __syncthreads();
  if (tid == 0) out[0] = (red[0] + red[1] + red[2] + red[3]) * (0.25f / 16.f);
}

// ---------------------------------------------------------------------------
extern "C" void kernel_launch(void* const* d_in, const int* in_sizes, int n_in,
                              void* d_out, int out_size, void* d_ws, size_t ws_size,
                              hipStream_t stream) {
  const float* x     = (const float*)d_in[0];
  const float* masks = (const float*)d_in[1];
  const float* W1    = (const float*)d_in[2];
  const float* ln_g  = (const float*)d_in[3];
  const float* ln_b  = (const float*)d_in[4];
  const float* W2    = (const float*)d_in[5];
  const float* b2    = (const float*)d_in[6];
  const float* emb   = (const float*)d_in[7];

  float* z_out = (float*)d_out;
  float* q_out = z_out + (size_t)NROWS * DD;
  float* loss_out = z_out + 2 * (size_t)NROWS * DD;

  char* ws = (char*)d_ws;
  u16*   Hh   = (u16*)(ws);                    //  33,554,432 B (8192 rows)
  u16*   Hl   = (u16*)(ws + 33554432);         //  33,554,432
  u16*   Xh   = (u16*)(ws + 67108864);         //  16,777,216
  u16*   Xl   = (u16*)(ws + 83886080);         //  16,777,216
  u16*   W1ht = (u16*)(ws + 100663296);        //   2,097,152
  u16*   W1lt = (u16*)(ws + 102760448);        //   2,097,152
  u16*   W2ht = (u16*)(ws + 104857600);        //   1,048,576
  u16*   W2lt = (u16*)(ws + 105906176);        //   1,048,576
  float* Pb   = (float*)(ws + 106954752);      //  16,777,216
  float* LE   = (float*)(ws + 123731968);      //   1,048,576
  float* KL   = (float*)(ws + 124780544);      //      65,536  -> total 124,846,080

  k_split_x<<<4096, 256, 0, stream>>>(x, Xh, Xl);
  k_split_wT<<<dim3(64, 16), 256, 0, stream>>>(W1, W1ht, W1lt, INCH, CH);
  k_split_wT<<<dim3(8, 64), 256, 0, stream>>>(W2, W2ht, W2lt, CH, DD);
  k_logemb<<<(MM * DD) / 256, 256, 0, stream>>>(emb, LE, MM * DD);

  for (int half = 0; half < 2; ++half) {
    const size_t xo = (size_t)half * HALF_ROWS * INCH;
    const size_t zo = (size_t)half * HALF_ROWS * DD;
    k_gemm1<<<dim3(16, 64), 256, 0, stream>>>(Xh + xo, Xl + xo, W1ht, W1lt, Hh, Hl);
    k_ln<<<HALF_ROWS, 256, 0, stream>>>(Hh, Hl, ln_g, ln_b);
    k_gemm2<<<dim3(2, 128), 256, 0, stream>>>(Hh, Hl, W2ht, W2lt, b2, z_out + zo, Pb + zo);
  }

  k_codebook<<<NROWS / 64, 256, 0, stream>>>(Pb, LE, emb, q_out, KL);
  k_loss<<<1, 256, 0, stream>>>(KL, masks, loss_out);
}

// Round 3
// 842.462 us; speedup vs baseline: 1.2930x; 1.2135x over previous
//
#include <hip/hip_runtime.h>
#include <math.h>

#define NROWS 16384   // B*T
#define HALF_ROWS 8192
#define INCH  512
#define CH    2048
#define DD    256
#define MM    1024

typedef unsigned short u16;
typedef short short8 __attribute__((ext_vector_type(8)));
typedef float f32x4 __attribute__((ext_vector_type(4)));

__device__ __forceinline__ u16 f2bf(float f) {
  unsigned u = __float_as_uint(f);
  return (u16)((u + 0x7fffu + ((u >> 16) & 1u)) >> 16);
}
__device__ __forceinline__ float bf2f(u16 h) {
  return __uint_as_float(((unsigned)h) << 16);
}
__device__ __forceinline__ void gload16(const u16* g, u16* lds) {
  __builtin_amdgcn_global_load_lds((const __attribute__((address_space(1))) void*)g,
                                   (__attribute__((address_space(3))) void*)lds, 16, 0, 0);
}

// ---------------------------------------------------------------------------
// split kernels: fp32 -> bf16 hi/lo pair
// ---------------------------------------------------------------------------
__global__ __launch_bounds__(256) void k_split_x(const float* __restrict__ x,
                                                 u16* __restrict__ xh, u16* __restrict__ xl) {
  const size_t i = ((size_t)blockIdx.x * 256 + threadIdx.x) * 8;
  float4 a = *(const float4*)(x + i);
  float4 b = *(const float4*)(x + i + 4);
  float v[8] = {a.x, a.y, a.z, a.w, b.x, b.y, b.z, b.w};
  unsigned hw[4], lw[4];
#pragma unroll
  for (int p = 0; p < 4; ++p) {
    u16 h0 = f2bf(v[2*p]), h1 = f2bf(v[2*p+1]);
    u16 l0 = f2bf(v[2*p] - bf2f(h0)), l1 = f2bf(v[2*p+1] - bf2f(h1));
    hw[p] = (unsigned)h0 | ((unsigned)h1 << 16);
    lw[p] = (unsigned)l0 | ((unsigned)l1 << 16);
  }
  *(uint4*)(xh + i) = make_uint4(hw[0], hw[1], hw[2], hw[3]);
  *(uint4*)(xl + i) = make_uint4(lw[0], lw[1], lw[2], lw[3]);
}

// src [R][C] fp32  ->  dh/dl [C][R] bf16 hi/lo   (transpose + split)
__global__ __launch_bounds__(256) void k_split_wT(const float* __restrict__ src,
                                                  u16* __restrict__ dh, u16* __restrict__ dl,
                                                  int R, int C) {
  __shared__ float t[32][33];
  const int tx = threadIdx.x & 31, ty = threadIdx.x >> 5;
  const int c0 = blockIdx.x * 32, r0 = blockIdx.y * 32;
#pragma unroll
  for (int i = 0; i < 4; ++i)
    t[ty + i * 8][tx] = src[(size_t)(r0 + ty + i * 8) * C + c0 + tx];
  __syncthreads();
#pragma unroll
  for (int i = 0; i < 4; ++i) {
    float v = t[tx][ty + i * 8];
    size_t o = (size_t)(c0 + ty + i * 8) * R + r0 + tx;
    u16 h = f2bf(v);
    dh[o] = h;
    dl[o] = f2bf(v - bf2f(h));
  }
}

// ---------------------------------------------------------------------------
// K1: H(split) = X @ W1 via split-bf16 MFMA. 128x128 tile, BK=32, 4 waves.
// ---------------------------------------------------------------------------
__global__ __launch_bounds__(256) void k_gemm1(const u16* __restrict__ Xh, const u16* __restrict__ Xl,
                                               const u16* __restrict__ W1ht, const u16* __restrict__ W1lt,
                                               u16* __restrict__ Hh, u16* __restrict__ Hl) {
  __shared__ u16 sm[2][2048 * 8];
  const int tid = threadIdx.x;
  const int lane = tid & 63, w = tid >> 6;
  const int wr = w >> 1, wc = w & 1;
  const int gm = blockIdx.y * 128, n0 = blockIdx.x * 128;

  const u16* srcbase = (w == 0) ? Xh : (w == 1) ? Xl : (w == 2) ? W1ht : W1lt;
  const int rowbase = (w < 2) ? gm : n0;

  f32x4 acc[4][4];
#pragma unroll
  for (int i = 0; i < 4; ++i)
#pragma unroll
    for (int j = 0; j < 4; ++j) acc[i][j] = (f32x4){0.f, 0.f, 0.f, 0.f};

  auto STAGE = [&](int buf, int kt) {
#pragma unroll
    for (int t = 0; t < 8; ++t) {
      int c = t * 64 + lane;
      int kc = c >> 7, r = c & 127;
      const u16* g = srcbase + ((size_t)(rowbase + r) << 9) + (kt << 5) + (kc << 3);
      gload16(g, &sm[buf][(w * 512 + t * 64) * 8]);
    }
  };

  STAGE(0, 0);
  for (int kt = 0; kt < 16; ++kt) {
    __syncthreads();
    if (kt + 1 < 16) STAGE((kt + 1) & 1, kt + 1);
    const u16* base = sm[kt & 1];
    const int lr = lane & 15, kc = lane >> 4;
    short8 ah[4], al[4], bh[4], bl[4];
#pragma unroll
    for (int i = 0; i < 4; ++i) {
      ah[i] = *(const short8*)(base + (kc * 128 + wr * 64 + i * 16 + lr) * 8);
      al[i] = *(const short8*)(base + (512 + kc * 128 + wr * 64 + i * 16 + lr) * 8);
      bh[i] = *(const short8*)(base + (1024 + kc * 128 + wc * 64 + i * 16 + lr) * 8);
      bl[i] = *(const short8*)(base + (1536 + kc * 128 + wc * 64 + i * 16 + lr) * 8);
    }
#pragma unroll
    for (int i = 0; i < 4; ++i)
#pragma unroll
      for (int j = 0; j < 4; ++j) {
        acc[i][j] = __builtin_amdgcn_mfma_f32_16x16x32_bf16(ah[i], bh[j], acc[i][j], 0, 0, 0);
        acc[i][j] = __builtin_amdgcn_mfma_f32_16x16x32_bf16(ah[i], bl[j], acc[i][j], 0, 0, 0);
        acc[i][j] = __builtin_amdgcn_mfma_f32_16x16x32_bf16(al[i], bh[j], acc[i][j], 0, 0, 0);
      }
  }

  const int rr = (lane >> 4) << 2, cc = lane & 15;
#pragma unroll
  for (int i = 0; i < 4; ++i)
#pragma unroll
    for (int j = 0; j < 4; ++j) {
#pragma unroll
      for (int reg = 0; reg < 4; ++reg) {
        size_t o = (size_t)(gm + wr * 64 + i * 16 + rr + reg) * CH + (n0 + wc * 64 + j * 16 + cc);
        float v = acc[i][j][reg];
        u16 h = f2bf(v);
        Hh[o] = h;
        Hl[o] = f2bf(v - bf2f(h));
      }
    }
}

// ---------------------------------------------------------------------------
// K2: in-place LayerNorm + ReLU on split H. One block per row.
// ---------------------------------------------------------------------------
__global__ __launch_bounds__(256) void k_ln(u16* __restrict__ Hh, u16* __restrict__ Hl,
                                            const float* __restrict__ g, const float* __restrict__ b) {
  __shared__ float red[8];
  const int row = blockIdx.x;
  const int tid = threadIdx.x;
  uint4* hp = (uint4*)(Hh + (size_t)row * CH);
  uint4* lp = (uint4*)(Hl + (size_t)row * CH);
  uint4 hh = hp[tid], ll = lp[tid];
  float f[8];
  {
    unsigned hw[4] = {hh.x, hh.y, hh.z, hh.w};
    unsigned lw[4] = {ll.x, ll.y, ll.z, ll.w};
#pragma unroll
    for (int p = 0; p < 4; ++p) {
      f[2*p]   = bf2f((u16)(hw[p] & 0xffffu)) + bf2f((u16)(lw[p] & 0xffffu));
      f[2*p+1] = bf2f((u16)(hw[p] >> 16))     + bf2f((u16)(lw[p] >> 16));
    }
  }
  float s = 0.f, ss = 0.f;
#pragma unroll
  for (int j = 0; j < 8; ++j) { s += f[j]; ss += f[j] * f[j]; }
#pragma unroll
  for (int m = 32; m; m >>= 1) { s += __shfl_xor(s, m); ss += __shfl_xor(ss, m); }
  if ((tid & 63) == 0) { red[(tid >> 6) * 2] = s; red[(tid >> 6) * 2 + 1] = ss; }
  __syncthreads();
  s  = red[0] + red[2] + red[4] + red[6];
  ss = red[1] + red[3] + red[5] + red[7];
  const float mu  = s * (1.f / CH);
  const float var = ss * (1.f / CH) - mu * mu;
  const float rinv = 1.f / sqrtf(var + 1e-5f);
  float4 g0 = ((const float4*)g)[tid * 2], g1 = ((const float4*)g)[tid * 2 + 1];
  float4 b0 = ((const float4*)b)[tid * 2], b1 = ((const float4*)b)[tid * 2 + 1];
  float gg[8] = {g0.x, g0.y, g0.z, g0.w, g1.x, g1.y, g1.z, g1.w};
  float bb[8] = {b0.x, b0.y, b0.z, b0.w, b1.x, b1.y, b1.z, b1.w};
  unsigned hw[4], lw[4];
#pragma unroll
  for (int p = 0; p < 4; ++p) {
    float y0 = fmaxf((f[2*p]   - mu) * rinv * gg[2*p]   + bb[2*p],   0.f);
    float y1 = fmaxf((f[2*p+1] - mu) * rinv * gg[2*p+1] + bb[2*p+1], 0.f);
    u16 h0 = f2bf(y0), h1 = f2bf(y1);
    u16 l0 = f2bf(y0 - bf2f(h0)), l1 = f2bf(y1 - bf2f(h1));
    hw[p] = (unsigned)h0 | ((unsigned)h1 << 16);
    lw[p] = (unsigned)l0 | ((unsigned)l1 << 16);
  }
  hp[tid] = make_uint4(hw[0], hw[1], hw[2], hw[3]);
  lp[tid] = make_uint4(lw[0], lw[1], lw[2], lw[3]);
}

// ---------------------------------------------------------------------------
// K3: Z = H @ W2 + b2, fused per-head log_softmax -> P. Split-bf16 MFMA.
// ---------------------------------------------------------------------------
__global__ __launch_bounds__(256) void k_gemm2(const u16* __restrict__ Hh, const u16* __restrict__ Hl,
                                               const u16* __restrict__ W2ht, const u16* __restrict__ W2lt,
                                               const float* __restrict__ b2,
                                               float* __restrict__ Z, float* __restrict__ P) {
  __shared__ u16 sm[2][1536 * 8];
  const int tid = threadIdx.x;
  const int lane = tid & 63, w = tid >> 6;
  const int gm = blockIdx.y * 64, n0 = blockIdx.x * 128;

  f32x4 acc[8];
#pragma unroll
  for (int j = 0; j < 8; ++j) acc[j] = (f32x4){0.f, 0.f, 0.f, 0.f};

  auto STAGE = [&](int buf, int kt) {
#pragma unroll
    for (int t = 0; t < 6; ++t) {
      int v = w * 384 + t * 64 + lane;
      bool isA = v < 512;
      int ca = v & 255, cb = v & 511;
      int kc = isA ? (ca >> 6) : (cb >> 7);
      int row = isA ? (gm + (ca & 63)) : (n0 + (cb & 127));
      const u16* sb = (v < 256) ? Hh : (v < 512) ? Hl : (v < 1024) ? W2ht : W2lt;
      const u16* g = sb + ((size_t)row << 11) + (kt << 5) + (kc << 3);
      gload16(g, &sm[buf][(w * 384 + t * 64) * 8]);
    }
  };

  STAGE(0, 0);
  for (int kt = 0; kt < 64; ++kt) {
    __syncthreads();
    if (kt + 1 < 64) STAGE((kt + 1) & 1, kt + 1);
    const u16* base = sm[kt & 1];
    const int lr = lane & 15, kc = lane >> 4;
    short8 ah = *(const short8*)(base + (kc * 64 + w * 16 + lr) * 8);
    short8 al = *(const short8*)(base + (256 + kc * 64 + w * 16 + lr) * 8);
    short8 bh[8], bl[8];
#pragma unroll
    for (int j = 0; j < 8; ++j) {
      bh[j] = *(const short8*)(base + (512 + kc * 128 + j * 16 + lr) * 8);
      bl[j] = *(const short8*)(base + (1024 + kc * 128 + j * 16 + lr) * 8);
    }
#pragma unroll
    for (int j = 0; j < 8; ++j) {
      acc[j] = __builtin_amdgcn_mfma_f32_16x16x32_bf16(ah, bh[j], acc[j], 0, 0, 0);
      acc[j] = __builtin_amdgcn_mfma_f32_16x16x32_bf16(ah, bl[j], acc[j], 0, 0, 0);
      acc[j] = __builtin_amdgcn_mfma_f32_16x16x32_bf16(al, bh[j], acc[j], 0, 0, 0);
    }
  }

  const int cc = lane & 15;
  float bias[8];
#pragma unroll
  for (int j = 0; j < 8; ++j) bias[j] = b2[n0 + j * 16 + cc];
#pragma unroll
  for (int j = 0; j < 8; ++j)
#pragma unroll
    for (int reg = 0; reg < 4; ++reg) acc[j][reg] += bias[j];

  const int rr = (lane >> 4) << 2;
#pragma unroll
  for (int reg = 0; reg < 4; ++reg) {
    const int row = gm + w * 16 + rr + reg;
#pragma unroll
    for (int hd = 0; hd < 2; ++hd) {
      float mx = fmaxf(fmaxf(acc[hd*4+0][reg], acc[hd*4+1][reg]),
                       fmaxf(acc[hd*4+2][reg], acc[hd*4+3][reg]));
#pragma unroll
      for (int m = 1; m <= 8; m <<= 1) mx = fmaxf(mx, __shfl_xor(mx, m));
      float se = expf(acc[hd*4+0][reg] - mx) + expf(acc[hd*4+1][reg] - mx) +
                 expf(acc[hd*4+2][reg] - mx) + expf(acc[hd*4+3][reg] - mx);
#pragma unroll
      for (int m = 1; m <= 8; m <<= 1) se += __shfl_xor(se, m);
      const float lse = mx + logf(se);
#pragma unroll
      for (int j4 = 0; j4 < 4; ++j4) {
        const int col = n0 + (hd * 4 + j4) * 16 + cc;
        const size_t o = (size_t)row * DD + col;
        const float zv = acc[hd*4+j4][reg];
        Z[o] = zv;
        P[o] = zv - lse;
      }
    }
  }
}

// ---------------------------------------------------------------------------
// K4a: from P: ex = exp(p) 2-split bf16, SELF = sum ex*p per row. Wave/row.
// ---------------------------------------------------------------------------
__global__ __launch_bounds__(256) void k_prep_ex(const float* __restrict__ P,
                                                 u16* __restrict__ EXh, u16* __restrict__ EXl,
                                                 float* __restrict__ SELF) {
  const int tid = threadIdx.x;
  const int lane = tid & 63;
  const int row = blockIdx.x * 4 + (tid >> 6);
  float4 p4 = *(const float4*)&P[(size_t)row * DD + lane * 4];
  float e0 = expf(p4.x), e1 = expf(p4.y), e2 = expf(p4.z), e3 = expf(p4.w);
  float s = e0 * p4.x + e1 * p4.y + e2 * p4.z + e3 * p4.w;
#pragma unroll
  for (int m = 32; m; m >>= 1) s += __shfl_xor(s, m);
  if (lane == 0) SELF[row] = s;
  u16 h0 = f2bf(e0), h1 = f2bf(e1), h2 = f2bf(e2), h3 = f2bf(e3);
  u16 l0 = f2bf(e0 - bf2f(h0)), l1 = f2bf(e1 - bf2f(h1));
  u16 l2 = f2bf(e2 - bf2f(h2)), l3 = f2bf(e3 - bf2f(h3));
  uint2 hv = make_uint2((unsigned)h0 | ((unsigned)h1 << 16), (unsigned)h2 | ((unsigned)h3 << 16));
  uint2 lv = make_uint2((unsigned)l0 | ((unsigned)l1 << 16), (unsigned)l2 | ((unsigned)l3 << 16));
  *(uint2*)&EXh[(size_t)row * DD + lane * 4] = hv;
  *(uint2*)&EXl[(size_t)row * DD + lane * 4] = lv;
}

// ---------------------------------------------------------------------------
// K4b: logE = log(emb), 3-split bf16 (hi/mid/lo), layout [1024][256]
// ---------------------------------------------------------------------------
__global__ __launch_bounds__(256) void k_prep_le(const float* __restrict__ E,
                                                 u16* __restrict__ LEh, u16* __restrict__ LEm,
                                                 u16* __restrict__ LEl) {
  const size_t i = ((size_t)blockIdx.x * 256 + threadIdx.x) * 4;
  float4 v4 = *(const float4*)&E[i];
  float v[4] = {logf(v4.x), logf(v4.y), logf(v4.z), logf(v4.w)};
  u16 h[4], m_[4], l[4];
#pragma unroll
  for (int e = 0; e < 4; ++e) {
    h[e] = f2bf(v[e]);
    float r1 = v[e] - bf2f(h[e]);
    m_[e] = f2bf(r1);
    float r2 = r1 - bf2f(m_[e]);
    l[e] = f2bf(r2);
  }
  *(uint2*)&LEh[i] = make_uint2((unsigned)h[0] | ((unsigned)h[1] << 16), (unsigned)h[2] | ((unsigned)h[3] << 16));
  *(uint2*)&LEm[i] = make_uint2((unsigned)m_[0] | ((unsigned)m_[1] << 16), (unsigned)m_[2] | ((unsigned)m_[3] << 16));
  *(uint2*)&LEl[i] = make_uint2((unsigned)l[0] | ((unsigned)l[1] << 16), (unsigned)l[2] | ((unsigned)l[3] << 16));
}

// ---------------------------------------------------------------------------
// K5: DOTS[N,1024] = EX @ LE^T via 5-term split MFMA (ex 2-split x logE 3-split)
// 128x128 tile, BK=32, K=256, single-buffer 2-barrier (40KB LDS -> 3 blk/CU)
// slabs (512 chunks each): 0 EXh, 1 EXl, 2 LEh, 3 LEm, 4 LEl; chunk=kc*128+r
// ---------------------------------------------------------------------------
__global__ __launch_bounds__(256) void k_dots(const u16* __restrict__ EXh, const u16* __restrict__ EXl,
                                              const u16* __restrict__ LEh, const u16* __restrict__ LEm,
                                              const u16* __restrict__ LEl,
                                              float* __restrict__ DOTS) {
  __shared__ u16 sm[2560 * 8];
  const int tid = threadIdx.x;
  const int lane = tid & 63, w = tid >> 6;
  const int wr = w >> 1, wc = w & 1;
  const int gm = blockIdx.y * 128, m0 = blockIdx.x * 128;

  f32x4 acc[4][4];
#pragma unroll
  for (int i = 0; i < 4; ++i)
#pragma unroll
    for (int j = 0; j < 4; ++j) acc[i][j] = (f32x4){0.f, 0.f, 0.f, 0.f};

  for (int kt = 0; kt < 8; ++kt) {
    __syncthreads();
#pragma unroll
    for (int t = 0; t < 10; ++t) {
      const int c = w * 640 + t * 64 + lane;
      const int slab = c >> 9;
      const int within = c & 511;
      const int kc = within >> 7, r = within & 127;
      const u16* src = (slab == 0) ? EXh : (slab == 1) ? EXl :
                       (slab == 2) ? LEh : (slab == 3) ? LEm : LEl;
      const int rowbase = (slab < 2) ? gm : m0;
      const u16* g = src + ((size_t)(rowbase + r) << 8) + (kt << 5) + (kc << 3);
      gload16(g, &sm[(w * 640 + t * 64) * 8]);
    }
    __syncthreads();
    const int lr = lane & 15, kc2 = lane >> 4;
    short8 eh[4], el[4], bh[4], bm[4], bl[4];
#pragma unroll
    for (int i = 0; i < 4; ++i) {
      eh[i] = *(const short8*)(sm + ((kc2 * 128 + wr * 64 + i * 16 + lr)) * 8);
      el[i] = *(const short8*)(sm + ((512 + kc2 * 128 + wr * 64 + i * 16 + lr)) * 8);
      bh[i] = *(const short8*)(sm + ((1024 + kc2 * 128 + wc * 64 + i * 16 + lr)) * 8);
      bm[i] = *(const short8*)(sm + ((1536 + kc2 * 128 + wc * 64 + i * 16 + lr)) * 8);
      bl[i] = *(const short8*)(sm + ((2048 + kc2 * 128 + wc * 64 + i * 16 + lr)) * 8);
    }
#pragma unroll
    for (int i = 0; i < 4; ++i)
#pragma unroll
      for (int j = 0; j < 4; ++j) {
        acc[i][j] = __builtin_amdgcn_mfma_f32_16x16x32_bf16(eh[i], bh[j], acc[i][j], 0, 0, 0);
        acc[i][j] = __builtin_amdgcn_mfma_f32_16x16x32_bf16(eh[i], bm[j], acc[i][j], 0, 0, 0);
        acc[i][j] = __builtin_amdgcn_mfma_f32_16x16x32_bf16(eh[i], bl[j], acc[i][j], 0, 0, 0);
        acc[i][j] = __builtin_amdgcn_mfma_f32_16x16x32_bf16(el[i], bh[j], acc[i][j], 0, 0, 0);
        acc[i][j] = __builtin_amdgcn_mfma_f32_16x16x32_bf16(el[i], bm[j], acc[i][j], 0, 0, 0);
      }
  }

  const int rr = (lane >> 4) << 2, cc = lane & 15;
#pragma unroll
  for (int i = 0; i < 4; ++i)
#pragma unroll
    for (int j = 0; j < 4; ++j)
#pragma unroll
      for (int reg = 0; reg < 4; ++reg) {
        const int row = gm + wr * 64 + i * 16 + rr + reg;
        const int col = m0 + wc * 64 + j * 16 + cc;
        DOTS[((size_t)row << 10) + col] = acc[i][j][reg];
      }
}

// ---------------------------------------------------------------------------
// K6: per row: argmax(dots) (first-index tie-break), KL = self - max,
// fused gather Q = E[argmax]. Wave per row.
// ---------------------------------------------------------------------------
__global__ __launch_bounds__(256) void k_scan(const float* __restrict__ DOTS,
                                              const float* __restrict__ SELF,
                                              const float* __restrict__ E,
                                              float* __restrict__ Q,
                                              float* __restrict__ KL) {
  const int tid = threadIdx.x;
  const int lane = tid & 63;
  const int row = blockIdx.x * 4 + (tid >> 6);

  float bv = -1e30f;
  int bi = 0x7fffffff;
#pragma unroll
  for (int q = 0; q < 4; ++q) {
    const int c0 = q * 256 + lane * 4;
    float4 v = *(const float4*)&DOTS[((size_t)row << 10) + c0];
    if (v.x > bv) { bv = v.x; bi = c0; }
    if (v.y > bv) { bv = v.y; bi = c0 + 1; }
    if (v.z > bv) { bv = v.z; bi = c0 + 2; }
    if (v.w > bv) { bv = v.w; bi = c0 + 3; }
  }
#pragma unroll
  for (int m = 32; m; m >>= 1) {
    float ov = __shfl_xor(bv, m);
    int   oi = __shfl_xor(bi, m);
    if (ov > bv || (ov == bv && oi < bi)) { bv = ov; bi = oi; }
  }
  if (lane == 0) KL[row] = SELF[row] - bv;
  float4 e4 = *(const float4*)&E[((size_t)bi << 8) + lane * 4];
  *(float4*)&Q[((size_t)row << 8) + lane * 4] = e4;
}

// ---------------------------------------------------------------------------
// K7: loss = 0.25/B * sum_n kl[n]*mask[n]
// ---------------------------------------------------------------------------
__global__ __launch_bounds__(256) void k_loss(const float* __restrict__ KL,
                                              const float* __restrict__ MASK,
                                              float* __restrict__ out) {
  __shared__ float red[4];
  const int tid = threadIdx.x;
  float s = 0.f;
  for (int i = tid; i < NROWS; i += 256) s += KL[i] * MASK[i];
#pragma unroll
  for (int m = 32; m; m >>= 1) s += __shfl_xor(s, m);
  if ((tid & 63) == 0) red[tid >> 6] = s;
  __syncthreads();
  if (tid == 0) out[0] = (red[0] + red[1] + red[2] + red[3]) * (0.25f / 16.f);
}

// ---------------------------------------------------------------------------
extern "C" void kernel_launch(void* const* d_in, const int* in_sizes, int n_in,
                              void* d_out, int out_size, void* d_ws, size_t ws_size,
                              hipStream_t stream) {
  const float* x     = (const float*)d_in[0];
  const float* masks = (const float*)d_in[1];
  const float* W1    = (const float*)d_in[2];
  const float* ln_g  = (const float*)d_in[3];
  const float* ln_b  = (const float*)d_in[4];
  const float* W2    = (const float*)d_in[5];
  const float* b2    = (const float*)d_in[6];
  const float* emb   = (const float*)d_in[7];

  float* z_out = (float*)d_out;
  float* q_out = z_out + (size_t)NROWS * DD;
  float* loss_out = z_out + 2 * (size_t)NROWS * DD;

  char* ws = (char*)d_ws;
  u16*   Hh   = (u16*)(ws);                    //  33,554,432 B (half: 8192 rows)
  u16*   Hl   = (u16*)(ws + 33554432);         //  33,554,432
  u16*   Xh   = (u16*)(ws + 67108864);         //  16,777,216
  u16*   Xl   = (u16*)(ws + 83886080);         //  16,777,216
  u16*   W1ht = (u16*)(ws + 100663296);        //   2,097,152
  u16*   W1lt = (u16*)(ws + 102760448);        //   2,097,152
  u16*   W2ht = (u16*)(ws + 104857600);        //   1,048,576
  u16*   W2lt = (u16*)(ws + 105906176);        //   1,048,576
  float* Pb   = (float*)(ws + 106954752);      //  16,777,216
  u16*   LEh  = (u16*)(ws + 123731968);        //     524,288
  u16*   LEm  = (u16*)(ws + 124256256);        //     524,288
  u16*   LEl  = (u16*)(ws + 124780544);        //     524,288
  float* KL   = (float*)(ws + 125304832);      //      65,536
  float* SELF = (float*)(ws + 125370368);      //      65,536  -> end 125,435,904
  // overlays (lifetimes disjoint):
  u16*   EXh  = (u16*)(ws + 67108864);         //  8,388,608 (over Xh; X dead after gemm1)
  u16*   EXl  = (u16*)(ws + 75497472);         //  8,388,608
  float* DOTS = (float*)(ws);                  // 67,108,864 (over Hh+Hl; H dead after gemm2)

  k_split_x<<<4096, 256, 0, stream>>>(x, Xh, Xl);
  k_split_wT<<<dim3(64, 16), 256, 0, stream>>>(W1, W1ht, W1lt, INCH, CH);
  k_split_wT<<<dim3(8, 64), 256, 0, stream>>>(W2, W2ht, W2lt, CH, DD);
  k_prep_le<<<256, 256, 0, stream>>>(emb, LEh, LEm, LEl);

  for (int half = 0; half < 2; ++half) {
    const size_t xo = (size_t)half * HALF_ROWS * INCH;
    const size_t zo = (size_t)half * HALF_ROWS * DD;
    k_gemm1<<<dim3(16, 64), 256, 0, stream>>>(Xh + xo, Xl + xo, W1ht, W1lt, Hh, Hl);
    k_ln<<<HALF_ROWS, 256, 0, stream>>>(Hh, Hl, ln_g, ln_b);
    k_gemm2<<<dim3(2, 128), 256, 0, stream>>>(Hh, Hl, W2ht, W2lt, b2, z_out + zo, Pb + zo);
  }

  k_prep_ex<<<4096, 256, 0, stream>>>(Pb, EXh, EXl, SELF);
  k_dots<<<dim3(8, 128), 256, 0, stream>>>(EXh, EXl, LEh, LEm, LEl, DOTS);
  k_scan<<<4096, 256, 0, stream>>>(DOTS, SELF, emb, q_out, KL);
  k_loss<<<1, 256, 0, stream>>>(KL, masks, loss_out);
}